// Round 5
// baseline (309.972 us; speedup 1.0000x reference)
//
#include <hip/hip_runtime.h>
#include <math.h>

// Causal linear attention, chunkwise. Shapes fixed by the reference:
// [N=4, L=4096, H=16, D=64], M=64, CHUNK=128, G=32.
static constexpr int Nn = 4, Ll = 4096, Hh = 16, Dd = 64, Mm = 64, Cc = 128, Gg = 32;
static constexpr int ROWS = Hh * Dd;  // 1024 floats: l-stride in [N,L,H,D]
#define EPS_ 1e-6f

typedef __bf16 bf16x8 __attribute__((ext_vector_type(8)));
typedef unsigned short us8 __attribute__((ext_vector_type(8)));
typedef float f32x4 __attribute__((ext_vector_type(4)));

__device__ __forceinline__ float phi(float x) {
    // elu(x)+1 = x+1 (x>0) else exp(x)
    return x > 0.0f ? x + 1.0f : __expf(x);
}

// bf16 round-to-nearest-even via bit trick
__device__ __forceinline__ unsigned short f2bf(float x) {
    unsigned u = __float_as_uint(x);
    return (unsigned short)((u + 0x7fffu + ((u >> 16) & 1u)) >> 16);
}
__device__ __forceinline__ float bf2f(unsigned short h) {
    return __uint_as_float(((unsigned)h) << 16);
}

// D = A*B + C, A,B bf16 16x32 / 32x16, C/D f32 16x16.
// A: row = lane&15, k = (lane>>4)*8+e ; B: col = lane&15, k = (lane>>4)*8+e
// C/D: col = lane&15, row = (lane>>4)*4 + reg   (HW-verified layout)
#define MFMA16(A, B, C)                                                      \
    __builtin_amdgcn_mfma_f32_16x16x32_bf16(__builtin_bit_cast(bf16x8, (A)), \
                                            __builtin_bit_cast(bf16x8, (B)), \
                                            (C), 0, 0, 0)

// 16B-granule XOR swizzles (consistent on write and read).
__device__ __forceinline__ int KIDX(int j, int d) {   // K [128 j][64 d]
    return j * 64 + ((((d >> 3) ^ j) & 7) << 3) + (d & 7);
}
__device__ __forceinline__ int VTIDX(int m, int j) {  // T-layout [rows][128 cols]
    return m * 128 + ((((j >> 3) ^ (m & 15) ^ (m >> 4)) & 15) << 3) + (j & 7);
}

__device__ __forceinline__ void load8(const float* p, float* xs) {
    float4 a = *(const float4*)p, b = *(const float4*)(p + 4);
    xs[0] = a.x; xs[1] = a.y; xs[2] = a.z; xs[3] = a.w;
    xs[4] = b.x; xs[5] = b.y; xs[6] = b.z; xs[7] = b.w;
}

// unpack 8 packed (hi|lo<<16) u32 -> hi us8, lo us8 via v_perm_b32
__device__ __forceinline__ void unpack8(const unsigned* p, us8& hi, us8& lo) {
    const uint4 a = *(const uint4*)p;
    const uint4 b = *(const uint4*)(p + 4);
    union { unsigned u[4]; us8 v; } H, L;
    H.u[0] = __builtin_amdgcn_perm(a.y, a.x, 0x05040100u);
    L.u[0] = __builtin_amdgcn_perm(a.y, a.x, 0x07060302u);
    H.u[1] = __builtin_amdgcn_perm(a.w, a.z, 0x05040100u);
    L.u[1] = __builtin_amdgcn_perm(a.w, a.z, 0x07060302u);
    H.u[2] = __builtin_amdgcn_perm(b.y, b.x, 0x05040100u);
    L.u[2] = __builtin_amdgcn_perm(b.y, b.x, 0x07060302u);
    H.u[3] = __builtin_amdgcn_perm(b.w, b.z, 0x05040100u);
    L.u[3] = __builtin_amdgcn_perm(b.w, b.z, 0x07060302u);
    hi = H.v; lo = L.v;
}

// ---------------------------------------------------------------------------
// Kernel 1: FUSED kv_state + exclusive prefix scan.
// Grid = 256 blocks = (n, h, mtile of 16 m-rows); block walks g = 0..31
// keeping the running KV state (16 m x 64 d) in fp32 MFMA accumulators.
// Per g: write the PRE-update acc packed bf16 hi|lo (exclusive prefix),
// then accumulate chunk g:  acc[m][d] += sum_c v[c][m] * phi(k[c][d]).
// Wave w owns d-tile w. The mtile-0 block also maintains the ksum prefix.
// Block remap: mtile = bid>>6, so the 4 sibling blocks of one (n,h) have
// bids 64 apart == same XCD (bid%8 equal) -> shared K chunk L2-hits.
// ---------------------------------------------------------------------------
struct KVPf {
    float4 ka0, kb0, ka1, kb1, ka2, kb2, ka3, kb3;  // K: 4 units x (c0,c0+1)
    float4 va, vb;                                  // V slice: (c0,c0+1)
};

#define KV_LD(A, B, C, D) (*(const float4*)((A) + (B) + (size_t)(C) * ROWS + (D)))

#define KV_PF_LOAD(G, P) do {                                                  \
    const size_t gb_ = ((size_t)(n * Ll + (G) * Cc) * Hh + h) * Dd;            \
    { const int u_ = tid;       const int d4_ = (u_ & 15) * 4, c0_ = (u_ >> 4) * 2; \
      P.ka0 = KV_LD(keys, gb_, c0_, d4_); P.kb0 = KV_LD(keys, gb_, c0_ + 1, d4_); } \
    { const int u_ = tid + 256; const int d4_ = (u_ & 15) * 4, c0_ = (u_ >> 4) * 2; \
      P.ka1 = KV_LD(keys, gb_, c0_, d4_); P.kb1 = KV_LD(keys, gb_, c0_ + 1, d4_); } \
    { const int u_ = tid + 512; const int d4_ = (u_ & 15) * 4, c0_ = (u_ >> 4) * 2; \
      P.ka2 = KV_LD(keys, gb_, c0_, d4_); P.kb2 = KV_LD(keys, gb_, c0_ + 1, d4_); } \
    { const int u_ = tid + 768; const int d4_ = (u_ & 15) * 4, c0_ = (u_ >> 4) * 2; \
      P.ka3 = KV_LD(keys, gb_, c0_, d4_); P.kb3 = KV_LD(keys, gb_, c0_ + 1, d4_); } \
    { const int m4_ = (tid & 3) * 4 + mt * 16, c0_ = (tid >> 2) * 2;           \
      P.va = KV_LD(values, gb_, c0_, m4_); P.vb = KV_LD(values, gb_, c0_ + 1, m4_); } \
} while (0)

#define STAGE_K_UNIT(IT, KA, KB) do {                                          \
    const int unit_ = tid + (IT) * 256;                                        \
    const int d4_ = (unit_ & 15) * 4, c0_ = (unit_ >> 4) * 2;                  \
    const float kaa_[4] = {KA.x, KA.y, KA.z, KA.w};                            \
    const float kbb_[4] = {KB.x, KB.y, KB.z, KB.w};                            \
    _Pragma("unroll")                                                          \
    for (int e = 0; e < 4; ++e) {                                              \
        const int idx = VTIDX(d4_ + e, c0_);                                   \
        const float pa = phi(kaa_[e]), pb = phi(kbb_[e]);                      \
        const unsigned ha = f2bf(pa), hb2 = f2bf(pb);                          \
        *(unsigned*)(KthS + idx) = ha | (hb2 << 16);                           \
        const unsigned la = f2bf(pa - bf2f((unsigned short)ha));               \
        const unsigned lb2 = f2bf(pb - bf2f((unsigned short)hb2));             \
        *(unsigned*)(KtlS + idx) = la | (lb2 << 16);                           \
    }                                                                          \
} while (0)

__global__ __launch_bounds__(256) void kv_scan_kernel(
    const float* __restrict__ keys, const float* __restrict__ values,
    unsigned* __restrict__ kvbuf, float* __restrict__ ksumbuf)
{
    __shared__ alignas(16) unsigned short KthS[64 * 128];  // kT [d][c] hi (16 KB)
    __shared__ alignas(16) unsigned short KtlS[64 * 128];  // kT [d][c] lo
    __shared__ alignas(16) unsigned short VmhS[16 * 128];  // vT slice [m][c] hi (4 KB)
    __shared__ alignas(16) unsigned short VmlS[16 * 128];  // vT slice [m][c] lo
    __shared__ float ksP[4 * 64];                          // ksum partials

    const int bid = blockIdx.x;
    const int mt = bid >> 6;          // m-tile 0..3 (siblings 64 apart -> same XCD)
    const int grp = bid & 63;
    const int n = grp >> 4, h = grp & 15;
    const int tid = threadIdx.x;
    const int w = tid >> 6, l = tid & 63;
    const int lr = l & 15, lg = l >> 4;

    KVPf pf;
    KV_PF_LOAD(0, pf);

    f32x4 acc = {0.f, 0.f, 0.f, 0.f};
    float runk = 0.f;  // ksum running prefix (valid: mt==0, tid<64)

    for (int g = 0; g < Gg; ++g) {
        // ---- stage chunk g from prefetch regs (transposed bf16 hi/lo) ----
        STAGE_K_UNIT(0, pf.ka0, pf.kb0);
        STAGE_K_UNIT(1, pf.ka1, pf.kb1);
        STAGE_K_UNIT(2, pf.ka2, pf.kb2);
        STAGE_K_UNIT(3, pf.ka3, pf.kb3);
        {
            const int m4 = (tid & 3) * 4, c0 = (tid >> 2) * 2;  // LOCAL m row
            const float vaa[4] = {pf.va.x, pf.va.y, pf.va.z, pf.va.w};
            const float vbb[4] = {pf.vb.x, pf.vb.y, pf.vb.z, pf.vb.w};
            #pragma unroll
            for (int e = 0; e < 4; ++e) {
                const int idx = VTIDX(m4 + e, c0);
                const unsigned ha = f2bf(vaa[e]), hb2 = f2bf(vbb[e]);
                *(unsigned*)(VmhS + idx) = ha | (hb2 << 16);
                const unsigned la = f2bf(vaa[e] - bf2f((unsigned short)ha));
                const unsigned lb2 = f2bf(vbb[e] - bf2f((unsigned short)hb2));
                *(unsigned*)(VmlS + idx) = la | (lb2 << 16);
            }
        }
        __syncthreads();

        // ---- prefetch chunk g+1 (hides HBM latency under MFMA phase) ----
        if (g + 1 < Gg) KV_PF_LOAD(g + 1, pf);

        // ---- EXCLUSIVE state write: pack pre-update acc ----
        {
            unsigned* kvp = kvbuf + ((size_t)((n * Gg + g) * Hh + h)) * 4096;
            #pragma unroll
            for (int r = 0; r < 4; ++r) {
                const unsigned hb = f2bf(acc[r]);
                const unsigned lb = f2bf(acc[r] - bf2f((unsigned short)hb));
                kvp[(mt * 16 + lg * 4 + r) * 64 + w * 16 + lr] = hb | (lb << 16);
            }
        }

        // ---- accumulate chunk g into acc (3-term hi/lo split MFMA) ----
        #pragma unroll
        for (int cs = 0; cs < 4; ++cs) {
            us8 a_h = *(const us8*)(VmhS + VTIDX(lr, cs * 32 + lg * 8));
            us8 a_l = *(const us8*)(VmlS + VTIDX(lr, cs * 32 + lg * 8));
            us8 b_h = *(const us8*)(KthS + VTIDX(w * 16 + lr, cs * 32 + lg * 8));
            us8 b_l = *(const us8*)(KtlS + VTIDX(w * 16 + lr, cs * 32 + lg * 8));
            acc = MFMA16(a_h, b_h, acc);
            acc = MFMA16(a_h, b_l, acc);
            acc = MFMA16(a_l, b_h, acc);
        }

        // ---- ksum partials (mtile-0 block only) ----
        if (mt == 0) {
            const int d = tid & 63, q = tid >> 6;
            float s = 0.f;
            #pragma unroll
            for (int sq = 0; sq < 4; ++sq) {
                us8 hh = *(const us8*)(KthS + VTIDX(d, q * 32 + sq * 8));
                us8 ll = *(const us8*)(KtlS + VTIDX(d, q * 32 + sq * 8));
                #pragma unroll
                for (int e = 0; e < 8; ++e) s += bf2f(hh[e]) + bf2f(ll[e]);
            }
            ksP[q * 64 + d] = s;
        }
        __syncthreads();
        // (safe: ksP reads below finish before any thread passes next g's
        //  first barrier; stage phase never writes ksP)
        if (mt == 0 && tid < 64) {
            const float sg = ksP[tid] + ksP[64 + tid] + ksP[128 + tid] + ksP[192 + tid];
            ksumbuf[((size_t)((n * Gg + g) * Hh + h)) * 64 + tid] = runk;  // exclusive
            runk += sg;
        }
    }
}

// ---------------------------------------------------------------------------
// Kernel 2: MFMA out kernel. One block per (n,g,h) chunk, 4 waves.
// Wave w owns 16-row tiles T = w and 7-w (balanced causal triangle).
// LDS ~74 KB -> 2 blocks/CU. KVprev B-fragments from global packed planes.
// Q loads hoisted to kernel start (latency hides under staging VALU).
// ---------------------------------------------------------------------------
__global__ __launch_bounds__(256, 2) void out_kernel(
    const float* __restrict__ queries,
    const float* __restrict__ keys,
    const float* __restrict__ values,
    const float* __restrict__ kvbuf,
    const float* __restrict__ ksumbuf,
    float* __restrict__ out)
{
    __shared__ alignas(16) unsigned short KhS[128 * 64];   // 16 KB phi(k) hi
    __shared__ alignas(16) unsigned short KlS[128 * 64];   // 16 KB phi(k) lo
    __shared__ alignas(16) unsigned short VthS[64 * 128];  // 16 KB V^T hi
    __shared__ alignas(16) unsigned short VtlS[64 * 128];  // 16 KB V^T lo
    __shared__ alignas(16) unsigned short SshS[4 * 512];   //  4 KB per-wave S hi
    __shared__ alignas(16) unsigned short SslS[4 * 512];   //  4 KB per-wave S lo
    __shared__ float kpreS[64];

    const int b = blockIdx.x;
    const int h = b & 15, g = (b >> 4) & 31, n = b >> 9;
    const int tid = threadIdx.x;
    const int w = tid >> 6, l = tid & 63;
    const int lr = l & 15, lg = l >> 4;

    const size_t chunkbase = ((size_t)(n * Ll + g * Cc) * Hh + h) * Dd;
    const size_t stateoff  = (size_t)((n * Gg + g) * Hh + h);

    // ---- hoisted Q loads: both row tiles, both k-slices (T14) ----
    float4 qv[2][2][2];  // [tt][ks][half]; all indices literal after unroll
    #pragma unroll
    for (int tt = 0; tt < 2; ++tt) {
        const int T = tt ? (7 - w) : w;
        #pragma unroll
        for (int ks = 0; ks < 2; ++ks) {
            const float* qp = queries + chunkbase +
                              (size_t)(T * 16 + lr) * ROWS + ks * 32 + lg * 8;
            qv[tt][ks][0] = *(const float4*)qp;
            qv[tt][ks][1] = *(const float4*)(qp + 4);
        }
    }

    // ---- stage kpre (exclusive prefix of column-sums of phi(k)) ----
    if (tid < 16)
        *(float4*)(kpreS + tid * 4) =
            *(const float4*)(ksumbuf + stateoff * 64 + tid * 4);

    // ---- stage phi(k) hi/lo, granule-swizzled (contiguous us8 writes) ----
    for (int t = tid; t < 1024; t += 256) {
        const int j = t >> 3, gb = t & 7;
        float xs[8];
        load8(keys + chunkbase + (size_t)j * ROWS + gb * 8, xs);
        us8 hh, ll;
        #pragma unroll
        for (int e = 0; e < 8; ++e) {
            const float p = phi(xs[e]);
            const unsigned short hb = f2bf(p);
            hh[e] = hb; ll[e] = f2bf(p - bf2f(hb));
        }
        const int base = KIDX(j, gb * 8);
        *(us8*)(KhS + base) = hh;
        *(us8*)(KlS + base) = ll;
    }
    // ---- stage V transposed hi/lo (row pairs -> packed b32 writes) ----
    for (int t = tid; t < 1024; t += 256) {
        const int jp = t >> 4, m4 = (t & 15) * 4;
        const int j0 = jp * 2;
        const float4 va = *(const float4*)(values + chunkbase + (size_t)j0 * ROWS + m4);
        const float4 vb = *(const float4*)(values + chunkbase + (size_t)(j0 + 1) * ROWS + m4);
        const float vaa[4] = {va.x, va.y, va.z, va.w};
        const float vbb[4] = {vb.x, vb.y, vb.z, vb.w};
        #pragma unroll
        for (int e = 0; e < 4; ++e) {
            const int idx = VTIDX(m4 + e, j0);  // j0 even -> aligned, same granule
            const unsigned hva = f2bf(vaa[e]), hvb = f2bf(vbb[e]);
            *(unsigned*)(VthS + idx) = hva | (hvb << 16);
            const unsigned lva = f2bf(vaa[e] - bf2f((unsigned short)hva));
            const unsigned lvb = f2bf(vbb[e] - bf2f((unsigned short)hvb));
            *(unsigned*)(VtlS + idx) = lva | (lvb << 16);
        }
    }
    __syncthreads();

    const unsigned* kvpk = (const unsigned*)kvbuf + stateoff * (size_t)4096;

    #pragma unroll
    for (int tt = 0; tt < 2; ++tt) {
        const int T = tt ? (7 - w) : w;  // balanced pairing: {w, 7-w}

        // ---- Q fragments (phi + split) and u = Q.kpre ----
        us8 qh[2], ql[2];
        float u = 0.f;
        #pragma unroll
        for (int ks = 0; ks < 2; ++ks) {
            const float4 xa = qv[tt][ks][0], xb = qv[tt][ks][1];
            const float xs[8] = {xa.x, xa.y, xa.z, xa.w, xb.x, xb.y, xb.z, xb.w};
            us8 hh, ll;
            #pragma unroll
            for (int e = 0; e < 8; ++e) {
                const float p = phi(xs[e]);
                u += p * kpreS[ks * 32 + lg * 8 + e];
                const unsigned short hb = f2bf(p);
                hh[e] = hb; ll[e] = f2bf(p - bf2f(hb));
            }
            qh[ks] = hh; ql[ks] = ll;
        }
        // reduce u over the 4 d-groups; afterwards lane i<16 holds u for row T*16+i
        u += __shfl_xor(u, 16, 64);
        u += __shfl_xor(u, 32, 64);

        // ---- inter: accO = Q . KVprev (B-frags from global packed planes) ----
        f32x4 accO[4];
        #pragma unroll
        for (int mt = 0; mt < 4; ++mt) {
            const unsigned* p = kvpk + (size_t)(mt * 16 + lr) * 64 + lg * 8;
            us8 bh0, bl0, bh1, bl1;
            unpack8(p, bh0, bl0);
            unpack8(p + 32, bh1, bl1);
            f32x4 acc = {0.f, 0.f, 0.f, 0.f};
            acc = MFMA16(qh[0], bh0, acc);
            acc = MFMA16(qh[0], bl0, acc);
            acc = MFMA16(ql[0], bh0, acc);
            acc = MFMA16(qh[1], bh1, acc);
            acc = MFMA16(qh[1], bl1, acc);
            acc = MFMA16(ql[1], bh1, acc);
            accO[mt] = acc;
        }

        // ---- causal j-blocks of 32 (two 16-col score tiles per block) ----
        f32x4 zp = {0.f, 0.f, 0.f, 0.f};
        const int nJb = (T + 2) >> 1;
        for (int Jb = 0; Jb < nJb; ++Jb) {
            const int Jlo = 2 * Jb, Jhi = 2 * Jb + 1;
            const bool hasHi = (Jhi <= T);

            f32x4 slo = {0.f, 0.f, 0.f, 0.f};
            f32x4 shi = {0.f, 0.f, 0.f, 0.f};
            __builtin_amdgcn_s_setprio(1);
            #pragma unroll
            for (int ks = 0; ks < 2; ++ks) {
                us8 bh = *(const us8*)(KhS + KIDX(Jlo * 16 + lr, ks * 32 + lg * 8));
                us8 bl = *(const us8*)(KlS + KIDX(Jlo * 16 + lr, ks * 32 + lg * 8));
                slo = MFMA16(qh[ks], bh, slo);
                slo = MFMA16(qh[ks], bl, slo);
                slo = MFMA16(ql[ks], bh, slo);
            }
            if (hasHi) {
                #pragma unroll
                for (int ks = 0; ks < 2; ++ks) {
                    us8 bh = *(const us8*)(KhS + KIDX(Jhi * 16 + lr, ks * 32 + lg * 8));
                    us8 bl = *(const us8*)(KlS + KIDX(Jhi * 16 + lr, ks * 32 + lg * 8));
                    shi = MFMA16(qh[ks], bh, shi);
                    shi = MFMA16(qh[ks], bl, shi);
                    shi = MFMA16(ql[ks], bh, shi);
                }
            }
            __builtin_amdgcn_s_setprio(0);
            // causal mask on the diagonal tile (C layout: row = lg*4+r, col = lr)
            if (Jlo == T) {
                #pragma unroll
                for (int r = 0; r < 4; ++r)
                    if (lr > lg * 4 + r) slo[r] = 0.f;
            }
            if (hasHi && Jhi == T) {
                #pragma unroll
                for (int r = 0; r < 4; ++r)
                    if (lr > lg * 4 + r) shi[r] = 0.f;
            }
            zp += slo;
            zp += shi;

            // ---- S -> bf16 hi/lo scratch (per-wave, single-buffered:
            //      DS ops are in-order per wave, so WAR within the wave is safe)
            unsigned short* sh = SshS + w * 512;
            unsigned short* sl = SslS + w * 512;
            #pragma unroll
            for (int r = 0; r < 4; ++r) {
                const int row = lg * 4 + r;
                const unsigned short h0 = f2bf(slo[r]);
                sh[row * 32 + lr]      = h0;
                sl[row * 32 + lr]      = f2bf(slo[r] - bf2f(h0));
                const unsigned short h1 = f2bf(shi[r]);
                sh[row * 32 + 16 + lr] = h1;
                sl[row * 32 + 16 + lr] = f2bf(shi[r] - bf2f(h1));
            }
            // wave-internal cross-lane LDS visibility
            asm volatile("s_waitcnt lgkmcnt(0)" ::: "memory");
            __builtin_amdgcn_sched_barrier(0);

            // ---- intra: accO += S . V over this 32-wide j-block ----
            us8 ah = *(const us8*)(sh + lr * 32 + lg * 8);
            us8 al = *(const us8*)(sl + lr * 32 + lg * 8);
            __builtin_amdgcn_s_setprio(1);
            #pragma unroll
            for (int mt = 0; mt < 4; ++mt) {
                us8 vh = *(const us8*)(VthS + VTIDX(mt * 16 + lr, Jb * 32 + lg * 8));
                us8 vl = *(const us8*)(VtlS + VTIDX(mt * 16 + lr, Jb * 32 + lg * 8));
                accO[mt] = MFMA16(ah, vh, accO[mt]);
                accO[mt] = MFMA16(ah, vl, accO[mt]);
                accO[mt] = MFMA16(al, vh, accO[mt]);
            }
            __builtin_amdgcn_s_setprio(0);
        }

        // ---- z = eps + u + rowsum(masked S): butterfly over the 16 columns ----
        #pragma unroll
        for (int r = 0; r < 4; ++r) {
            float s = zp[r];
            s += __shfl_xor(s, 1, 64);
            s += __shfl_xor(s, 2, 64);
            s += __shfl_xor(s, 4, 64);
            s += __shfl_xor(s, 8, 64);
            zp[r] = s;
        }

        const size_t ob = ((size_t)(n * Ll + g * Cc + T * 16) * Hh + h) * Mm;
        #pragma unroll
        for (int r = 0; r < 4; ++r) {
            const int row = lg * 4 + r;
            const float ur = __shfl(u, row, 64);
            const float iz = 1.0f / (EPS_ + ur + zp[r]);
            #pragma unroll
            for (int mt = 0; mt < 4; ++mt)
                out[ob + (size_t)row * ROWS + mt * 16 + lr] = accO[mt][r] * iz;
        }
    }
}

extern "C" void kernel_launch(void* const* d_in, const int* in_sizes, int n_in,
                              void* d_out, int out_size, void* d_ws, size_t ws_size,
                              hipStream_t stream) {
    const float* q = (const float*)d_in[0];
    const float* k = (const float*)d_in[1];
    const float* v = (const float*)d_in[2];
    float* out = (float*)d_out;

    // workspace: packed exclusive KV states (33.5 MB) + exclusive ksum (0.5 MB)
    unsigned* kvbuf = (unsigned*)d_ws;
    float* ksumbuf  = (float*)d_ws + (size_t)Nn * Gg * Hh * Dd * Mm;

    kv_scan_kernel<<<Nn * Hh * 4, 256, 0, stream>>>(k, v, kvbuf, ksumbuf);

    out_kernel<<<Nn * Gg * Hh, 256, 0, stream>>>(q, k, v, (const float*)kvbuf,
                                                 ksumbuf, out);
}